// Round 16
// baseline (166.910 us; speedup 1.0000x reference)
//
#include <hip/hip_runtime.h>
#include <hip/hip_bf16.h>

#define BATCH 8192
#define NV 512
#define LD 64

typedef __attribute__((ext_vector_type(8))) short bf16x8;
typedef __attribute__((ext_vector_type(4))) float f32x4;

// ws layout (floats): [0..511] r1bits, [512] r2sum, [513] ticket

static __device__ __forceinline__ bf16x8 cvt8(float4 f0, float4 f1) {
  bf16x8 r;
  r[0] = (short)__bfloat16_as_ushort(__float2bfloat16(f0.x));
  r[1] = (short)__bfloat16_as_ushort(__float2bfloat16(f0.y));
  r[2] = (short)__bfloat16_as_ushort(__float2bfloat16(f0.z));
  r[3] = (short)__bfloat16_as_ushort(__float2bfloat16(f0.w));
  r[4] = (short)__bfloat16_as_ushort(__float2bfloat16(f1.x));
  r[5] = (short)__bfloat16_as_ushort(__float2bfloat16(f1.y));
  r[6] = (short)__bfloat16_as_ushort(__float2bfloat16(f1.z));
  r[7] = (short)__bfloat16_as_ushort(__float2bfloat16(f1.w));
  return r;
}

static __device__ __forceinline__ float sq16(float4 a, float4 b, float4 c, float4 d) {
  float s = 0.f;
  s = fmaf(a.x, a.x, s); s = fmaf(a.y, a.y, s); s = fmaf(a.z, a.z, s); s = fmaf(a.w, a.w, s);
  s = fmaf(b.x, b.x, s); s = fmaf(b.y, b.y, s); s = fmaf(b.z, b.z, s); s = fmaf(b.w, b.w, s);
  s = fmaf(c.x, c.x, s); s = fmaf(c.y, c.y, s); s = fmaf(c.z, c.z, s); s = fmaf(c.w, c.w, s);
  s = fmaf(d.x, d.x, s); s = fmaf(d.y, d.y, s); s = fmaf(d.z, d.z, s); s = fmaf(d.w, d.w, s);
  return s;
}

__global__ __launch_bounds__(512) void init_kernel(unsigned* __restrict__ r1bits,
                                                   float* __restrict__ r2sum,
                                                   unsigned* __restrict__ ticket) {
  r1bits[threadIdx.x] = 0xFFFFFFFFu;  // uint-max init for atomicMin
  if (threadIdx.x == 0) { *r2sum = 0.f; *ticket = 0u; }
}

// Block: 16 x-rows x all 512 cols. 8 waves; wave w owns cols [w*64, w*64+64).
// Norms computed inline in f32 from the fragment loads; fragments cast to bf16
// for mfma_f32_16x16x32_bf16. D: col=lane&15, row=(lane>>4)*4+reg [m89/m91].
// Last block (ticket) folds the r1/r2 means into out — no finalize launch.
__global__ __launch_bounds__(512) void dist_kernel(const float* __restrict__ x,
                                                   const float* __restrict__ p,
                                                   float* __restrict__ out,
                                                   unsigned* __restrict__ r1bits,
                                                   float* __restrict__ r2sum,
                                                   unsigned* __restrict__ ticket) {
  const int tid = threadIdx.x;
  const int w = tid >> 6, lane = tid & 63;
  const int lhi = lane >> 4, llo = lane & 15;
  const int r0 = blockIdx.x << 4;   // 16 rows per block
  const int colbase = w * 64;

  __shared__ float xn_s[8][16];
  __shared__ float r2buf[8][16];
  __shared__ float sumbuf[8];
  __shared__ unsigned flag;

  // ---- A fragments + x-row norm (row r0+llo) in f32 ----
  const float* arow = x + (r0 + llo) * LD;
  float4 xa0 = *(const float4*)(arow + lhi * 8);
  float4 xa1 = *(const float4*)(arow + lhi * 8 + 4);
  float4 xa2 = *(const float4*)(arow + 32 + lhi * 8);
  float4 xa3 = *(const float4*)(arow + 32 + lhi * 8 + 4);

  float s = sq16(xa0, xa1, xa2, xa3);
  s += __shfl_xor(s, 16);
  s += __shfl_xor(s, 32);           // ||x_row||^2
  if (lhi == 0) xn_s[w][llo] = s;   // within-wave write/read

  bf16x8 a0 = cvt8(xa0, xa1), a1 = cvt8(xa2, xa3);

  // ---- B fragments + p-norms + MFMA ----
  f32x4 acc[4];
  float pns[4];
#pragma unroll
  for (int t = 0; t < 4; ++t) {
    const float* prow = p + (colbase + t * 16 + llo) * LD;
    float4 pf0 = *(const float4*)(prow + lhi * 8);
    float4 pf1 = *(const float4*)(prow + lhi * 8 + 4);
    float4 pf2 = *(const float4*)(prow + 32 + lhi * 8);
    float4 pf3 = *(const float4*)(prow + 32 + lhi * 8 + 4);
    float ps = sq16(pf0, pf1, pf2, pf3);
    ps += __shfl_xor(ps, 16);
    ps += __shfl_xor(ps, 32);       // ||p_col||^2, in exactly the lane that needs it
    pns[t] = ps;
    f32x4 z = {0.f, 0.f, 0.f, 0.f};
    z = __builtin_amdgcn_mfma_f32_16x16x32_bf16(a0, cvt8(pf0, pf1), z, 0, 0, 0);
    z = __builtin_amdgcn_mfma_f32_16x16x32_bf16(a1, cvt8(pf2, pf3), z, 0, 0, 0);
    acc[t] = z;
  }

  float xnr[4];
#pragma unroll
  for (int r = 0; r < 4; ++r) xnr[r] = xn_s[w][lhi * 4 + r];

  // ---- epilogue: dist = sqrt(max(xn + pn - 2*dot, 0)) + reductions ----
  float rmin[4] = {3.4e38f, 3.4e38f, 3.4e38f, 3.4e38f};
#pragma unroll
  for (int t = 0; t < 4; ++t) {
    const int col = colbase + t * 16 + llo;
    float cm = 3.4e38f;
#pragma unroll
    for (int r = 0; r < 4; ++r) {
      float d2 = xnr[r] + pns[t] - 2.f * acc[t][r];
      float dist = sqrtf(fmaxf(d2, 0.f));
      out[(long)(r0 + lhi * 4 + r) * NV + col] = dist;
      cm = fminf(cm, dist);
      rmin[r] = fminf(rmin[r], dist);
    }
    cm = fminf(cm, __shfl_xor(cm, 16));
    cm = fminf(cm, __shfl_xor(cm, 32));
    if (lane < 16) atomicMin(&r1bits[colbase + t * 16 + lane], __float_as_uint(cm));
  }

#pragma unroll
  for (int r = 0; r < 4; ++r) {
    float v = rmin[r];
    v = fminf(v, __shfl_xor(v, 1));
    v = fminf(v, __shfl_xor(v, 2));
    v = fminf(v, __shfl_xor(v, 4));
    v = fminf(v, __shfl_xor(v, 8));
    if (llo == 0) r2buf[w][lhi * 4 + r] = v;
  }
  __syncthreads();
  if (tid < 16) {
    float v = r2buf[0][tid];
#pragma unroll
    for (int ww = 1; ww < 8; ++ww) v = fminf(v, r2buf[ww][tid]);
    v += __shfl_xor(v, 1);
    v += __shfl_xor(v, 2);
    v += __shfl_xor(v, 4);
    v += __shfl_xor(v, 8);
    if (tid == 0) atomicAdd(r2sum, v);
  }

  // ---- last-block finalize (drops a kernel launch) ----
  __threadfence();                   // each thread drains its own device atomics
  __syncthreads();                   // all fences complete before the ticket
  if (tid == 0) flag = atomicAdd(ticket, 1u);
  __syncthreads();
  if (flag == (unsigned)(gridDim.x - 1)) {
    // device-scope RMW reads (XCD-coherence-safe, G16)
    unsigned bits = atomicMin(&r1bits[tid], 0xFFFFFFFFu);  // non-destructive read
    float val = __uint_as_float(bits);
#pragma unroll
    for (int o = 1; o < 64; o <<= 1) val += __shfl_xor(val, o);
    if (lane == 0) sumbuf[w] = val;
    __syncthreads();
    if (tid == 0) {
      float total = 0.f;
#pragma unroll
      for (int ww = 0; ww < 8; ++ww) total += sumbuf[ww];
      out[(long)BATCH * NV] = total / (float)NV;
      float r2 = atomicAdd(r2sum, 0.f);                    // device-scope read
      out[(long)BATCH * NV + 1] = r2 / (float)BATCH;
    }
  }
}

extern "C" void kernel_launch(void* const* d_in, const int* in_sizes, int n_in,
                              void* d_out, int out_size, void* d_ws, size_t ws_size,
                              hipStream_t stream) {
  const float* x = (const float*)d_in[0];
  const float* p = (const float*)d_in[1];
  float* out = (float*)d_out;
  unsigned* r1bits = (unsigned*)d_ws;
  float* r2sum = (float*)d_ws + 512;
  unsigned* ticket = (unsigned*)d_ws + 513;

  hipLaunchKernelGGL(init_kernel, dim3(1), dim3(512), 0, stream, r1bits, r2sum, ticket);
  hipLaunchKernelGGL(dist_kernel, dim3(BATCH / 16), dim3(512), 0, stream,
                     x, p, out, r1bits, r2sum, ticket);
}

// Round 17
// 84.644 us; speedup vs baseline: 1.9719x; 1.9719x over previous
//
#include <hip/hip_runtime.h>
#include <hip/hip_bf16.h>

#define BATCH 8192
#define NV 512
#define LD 64

typedef __attribute__((ext_vector_type(8))) short bf16x8;
typedef __attribute__((ext_vector_type(4))) float f32x4;

// ws layout (floats): [0..511] r1bits, [512] r2sum

static __device__ __forceinline__ bf16x8 cvt8(float4 f0, float4 f1) {
  bf16x8 r;
  r[0] = (short)__bfloat16_as_ushort(__float2bfloat16(f0.x));
  r[1] = (short)__bfloat16_as_ushort(__float2bfloat16(f0.y));
  r[2] = (short)__bfloat16_as_ushort(__float2bfloat16(f0.z));
  r[3] = (short)__bfloat16_as_ushort(__float2bfloat16(f0.w));
  r[4] = (short)__bfloat16_as_ushort(__float2bfloat16(f1.x));
  r[5] = (short)__bfloat16_as_ushort(__float2bfloat16(f1.y));
  r[6] = (short)__bfloat16_as_ushort(__float2bfloat16(f1.z));
  r[7] = (short)__bfloat16_as_ushort(__float2bfloat16(f1.w));
  return r;
}

static __device__ __forceinline__ float sq16(float4 a, float4 b, float4 c, float4 d) {
  float s = 0.f;
  s = fmaf(a.x, a.x, s); s = fmaf(a.y, a.y, s); s = fmaf(a.z, a.z, s); s = fmaf(a.w, a.w, s);
  s = fmaf(b.x, b.x, s); s = fmaf(b.y, b.y, s); s = fmaf(b.z, b.z, s); s = fmaf(b.w, b.w, s);
  s = fmaf(c.x, c.x, s); s = fmaf(c.y, c.y, s); s = fmaf(c.z, c.z, s); s = fmaf(c.w, c.w, s);
  s = fmaf(d.x, d.x, s); s = fmaf(d.y, d.y, s); s = fmaf(d.z, d.z, s); s = fmaf(d.w, d.w, s);
  return s;
}

__global__ __launch_bounds__(512) void init_kernel(unsigned* __restrict__ r1bits,
                                                   float* __restrict__ r2sum) {
  r1bits[threadIdx.x] = 0x7f800000u;  // +inf bits (valid for non-negative float mins)
  if (threadIdx.x == 0) *r2sum = 0.f;
}

// Block: 16 x-rows x all 512 cols. 8 waves; wave w owns cols [w*64, w*64+64).
// Norms computed inline in f32 from the fragment loads; fragments cast to bf16
// for mfma_f32_16x16x32_bf16. D: col=lane&15, row=(lane>>4)*4+reg [m89/m91].
// NOTE (round 16 lesson): do NOT fuse the finalize via ticket+__threadfence —
// per-block device fences force serialized L2 writebacks (~30x kernel slowdown).
// The separate tiny finalize launch is cheaper than in-kernel coherence.
__global__ __launch_bounds__(512) void dist_kernel(const float* __restrict__ x,
                                                   const float* __restrict__ p,
                                                   float* __restrict__ out,
                                                   unsigned* __restrict__ r1bits,
                                                   float* __restrict__ r2sum) {
  const int tid = threadIdx.x;
  const int w = tid >> 6, lane = tid & 63;
  const int lhi = lane >> 4, llo = lane & 15;
  const int r0 = blockIdx.x << 4;   // 16 rows per block
  const int colbase = w * 64;

  __shared__ float xn_s[8][16];
  __shared__ float r2buf[8][16];

  // ---- A fragments + x-row norm (row r0+llo) in f32 ----
  const float* arow = x + (r0 + llo) * LD;
  float4 xa0 = *(const float4*)(arow + lhi * 8);
  float4 xa1 = *(const float4*)(arow + lhi * 8 + 4);
  float4 xa2 = *(const float4*)(arow + 32 + lhi * 8);
  float4 xa3 = *(const float4*)(arow + 32 + lhi * 8 + 4);

  float s = sq16(xa0, xa1, xa2, xa3);
  s += __shfl_xor(s, 16);
  s += __shfl_xor(s, 32);           // ||x_row||^2
  if (lhi == 0) xn_s[w][llo] = s;   // within-wave write/read (no barrier needed)

  bf16x8 a0 = cvt8(xa0, xa1), a1 = cvt8(xa2, xa3);

  // ---- B fragments + p-norms + MFMA ----
  f32x4 acc[4];
  float pns[4];
#pragma unroll
  for (int t = 0; t < 4; ++t) {
    const float* prow = p + (colbase + t * 16 + llo) * LD;
    float4 pf0 = *(const float4*)(prow + lhi * 8);
    float4 pf1 = *(const float4*)(prow + lhi * 8 + 4);
    float4 pf2 = *(const float4*)(prow + 32 + lhi * 8);
    float4 pf3 = *(const float4*)(prow + 32 + lhi * 8 + 4);
    float ps = sq16(pf0, pf1, pf2, pf3);
    ps += __shfl_xor(ps, 16);
    ps += __shfl_xor(ps, 32);       // ||p_col||^2, in exactly the lane that needs it
    pns[t] = ps;
    f32x4 z = {0.f, 0.f, 0.f, 0.f};
    z = __builtin_amdgcn_mfma_f32_16x16x32_bf16(a0, cvt8(pf0, pf1), z, 0, 0, 0);
    z = __builtin_amdgcn_mfma_f32_16x16x32_bf16(a1, cvt8(pf2, pf3), z, 0, 0, 0);
    acc[t] = z;
  }

  float xnr[4];
#pragma unroll
  for (int r = 0; r < 4; ++r) xnr[r] = xn_s[w][lhi * 4 + r];

  // ---- epilogue: dist = sqrt(max(xn + pn - 2*dot, 0)) + reductions ----
  float rmin[4] = {3.4e38f, 3.4e38f, 3.4e38f, 3.4e38f};
#pragma unroll
  for (int t = 0; t < 4; ++t) {
    const int col = colbase + t * 16 + llo;
    float cm = 3.4e38f;
#pragma unroll
    for (int r = 0; r < 4; ++r) {
      float d2 = xnr[r] + pns[t] - 2.f * acc[t][r];
      float dist = sqrtf(fmaxf(d2, 0.f));
      out[(long)(r0 + lhi * 4 + r) * NV + col] = dist;
      cm = fminf(cm, dist);
      rmin[r] = fminf(rmin[r], dist);
    }
    cm = fminf(cm, __shfl_xor(cm, 16));
    cm = fminf(cm, __shfl_xor(cm, 32));
    if (lane < 16) atomicMin(&r1bits[colbase + t * 16 + lane], __float_as_uint(cm));
  }

#pragma unroll
  for (int r = 0; r < 4; ++r) {
    float v = rmin[r];
    v = fminf(v, __shfl_xor(v, 1));
    v = fminf(v, __shfl_xor(v, 2));
    v = fminf(v, __shfl_xor(v, 4));
    v = fminf(v, __shfl_xor(v, 8));
    if (llo == 0) r2buf[w][lhi * 4 + r] = v;
  }
  __syncthreads();
  if (tid < 16) {
    float v = r2buf[0][tid];
#pragma unroll
    for (int ww = 1; ww < 8; ++ww) v = fminf(v, r2buf[ww][tid]);
    v += __shfl_xor(v, 1);
    v += __shfl_xor(v, 2);
    v += __shfl_xor(v, 4);
    v += __shfl_xor(v, 8);
    if (tid == 0) atomicAdd(r2sum, v);
  }
}

__global__ __launch_bounds__(512) void finalize_kernel(const unsigned* __restrict__ r1bits,
                                                       const float* __restrict__ r2sum,
                                                       float* __restrict__ out) {
  int tid = threadIdx.x;
  float val = __uint_as_float(r1bits[tid]);
#pragma unroll
  for (int o = 32; o; o >>= 1) val += __shfl_xor(val, o);
  __shared__ float ws[8];
  if ((tid & 63) == 0) ws[tid >> 6] = val;
  __syncthreads();
  if (tid == 0) {
    float sum = 0.f;
    for (int w = 0; w < 8; ++w) sum += ws[w];
    out[(long)BATCH * NV] = sum / (float)NV;
    out[(long)BATCH * NV + 1] = r2sum[0] / (float)BATCH;
  }
}

extern "C" void kernel_launch(void* const* d_in, const int* in_sizes, int n_in,
                              void* d_out, int out_size, void* d_ws, size_t ws_size,
                              hipStream_t stream) {
  const float* x = (const float*)d_in[0];
  const float* p = (const float*)d_in[1];
  float* out = (float*)d_out;
  unsigned* r1bits = (unsigned*)d_ws;
  float* r2sum = (float*)d_ws + 512;

  hipLaunchKernelGGL(init_kernel, dim3(1), dim3(512), 0, stream, r1bits, r2sum);
  hipLaunchKernelGGL(dist_kernel, dim3(BATCH / 16), dim3(512), 0, stream,
                     x, p, out, r1bits, r2sum);
  hipLaunchKernelGGL(finalize_kernel, dim3(1), dim3(512), 0, stream,
                     r1bits, r2sum, out);
}